// Round 1
// baseline (3930.414 us; speedup 1.0000x reference)
//
#include <hip/hip_runtime.h>
#include <math.h>

#define EMB 128
#define NR 6
#define NS 7
#define NB 8
#define TL 128   // triplets per block in the MFMA bilinear kernel
#define EPB 8    // edges per block-iteration in edge_w

typedef __attribute__((ext_vector_type(8))) short short8;   // 8 bf16 = 4 VGPR
typedef __attribute__((ext_vector_type(4))) float floatx4;  // MFMA C/D

__device__ __forceinline__ short f2bf(float f) {  // fp32 -> bf16 RNE
  unsigned int u = __float_as_uint(f);
  u = u + 0x7fff + ((u >> 16) & 1);
  return (short)(u >> 16);
}

// ---------------------------------------------------------------------------
__global__ void zero_kernel(float4* __restrict__ p, long n4) {
  long i = (long)blockIdx.x * blockDim.x + threadIdx.x;
  long stride = (long)gridDim.x * blockDim.x;
  float4 z; z.x = z.y = z.z = z.w = 0.f;
  for (; i < n4; i += stride) p[i] = z;
}

// W_bilin fp32 -> bf16 (same flat layout [i][j][k])
__global__ void wcvt_kernel(const float* __restrict__ w, short* __restrict__ o,
                            int n) {
  int i = blockIdx.x * 256 + threadIdx.x;
  if (i < n) o[i] = f2bf(w[i]);
}

// ---------------------------------------------------------------------------
// w = (rbf @ W_rbf) * silu(m @ W_m + b_m)        [E, EMB]
// v2: 8 edges per iteration. 8 consecutive m-rows are 4KB contiguous ->
// one coalesced float4 per thread stages all of them; 8 independent FMA
// chains per thread; 3 barriers per 8 edges (was 16).
// ---------------------------------------------------------------------------
__global__ __launch_bounds__(256) void edge_w_kernel(
    const float* __restrict__ rbf, const float* __restrict__ m,
    const float* __restrict__ W_rbf, const float* __restrict__ W_m,
    const float* __restrict__ b_m, float* __restrict__ w_out, int E) {
  __shared__ float ms[EPB * EMB];    // 4 KB staged m rows
  __shared__ float rs[EPB * 8];      // rbf rows, stride 8
  __shared__ float pacc[EPB * EMB];  // 4 KB cross-h partials

  const int tid = threadIdx.x;
  const int i = tid & 127;
  const int h = tid >> 7;

  float Wreg[64];
#pragma unroll
  for (int kk = 0; kk < 64; ++kk) Wreg[kk] = W_m[(h * 64 + kk) * EMB + i];
  float wr[NR];
#pragma unroll
  for (int r = 0; r < NR; ++r) wr[r] = W_rbf[r * EMB + i];
  const float bm = b_m[i];

  const int ngrp = (E + EPB - 1) / EPB;
  for (int g = blockIdx.x; g < ngrp; g += gridDim.x) {
    const long e0 = (long)g * EPB;
    const int nv = min(EPB, (int)(E - e0));
    __syncthreads();  // previous iteration's ms/pacc/rs fully consumed
    if (nv == EPB) {
      ((float4*)ms)[tid] = ((const float4*)(m + e0 * EMB))[tid];
    } else {
      int er = (tid * 4) >> 7;
      if (er < nv) ((float4*)ms)[tid] = ((const float4*)(m + e0 * EMB))[tid];
    }
    if (tid < EPB * NR) {
      int er = tid / NR, r = tid - er * NR;
      if (er < nv) rs[er * 8 + r] = rbf[(e0 + er) * NR + r];
    }
    __syncthreads();

    float acc[EPB];
#pragma unroll
    for (int er = 0; er < EPB; ++er) acc[er] = 0.f;
    const float4* mv4 = (const float4*)ms;  // index: er*32 + h*16 + q
#pragma unroll
    for (int q = 0; q < 16; ++q) {
#pragma unroll
      for (int er = 0; er < EPB; ++er) {
        float4 mv = mv4[er * 32 + h * 16 + q];  // broadcast LDS read
        acc[er] += Wreg[q * 4 + 0] * mv.x + Wreg[q * 4 + 1] * mv.y +
                   Wreg[q * 4 + 2] * mv.z + Wreg[q * 4 + 3] * mv.w;
      }
    }
    if (h == 1) {
#pragma unroll
      for (int er = 0; er < EPB; ++er) pacc[er * EMB + i] = acc[er];
    }
    __syncthreads();
    if (h == 0) {
#pragma unroll
      for (int er = 0; er < EPB; ++er) {
        if (er < nv) {
          float x = acc[er] + pacc[er * EMB + i] + bm;
          float sig = 1.f / (1.f + expf(-x));
          float act = x * sig;
          float ar = 0.f;
#pragma unroll
          for (int r = 0; r < NR; ++r) ar += wr[r] * rs[er * 8 + r];
          w_out[(e0 + er) * EMB + i] = ar * act;
        }
      }
    }
  }
}

// ---------------------------------------------------------------------------
// MFMA triplet kernel v2. 128 triplets/block, 512 threads = 8 waves.
// Wave wv owns M-tiles (wv>>2)*4..+3 and N-tiles (wv&3)*2..+1.
// CHANGES vs v1:
//  - wS (32KB LDS W_bilin staging) removed. B fragments are loaded directly
//    global->register from the L2-resident bf16 W_bilin (16B/lane,
//    immediate-offset addressing off 2 base pointers). The j-loop runs with
//    ZERO barriers (was 16 full-drain barriers/block).
//  - ks-outer / j-inner: only 4 A-frags live (16 VGPR vs 64), keeping total
//    VGPR <= 128 so 2 blocks/CU stay resident (__launch_bounds__(512,4)).
//    Per-(ks,j) partial MFMA products are scaled by sbf[l,j] in fp32 and
//    accumulated -- identical by linearity to scaling K-complete sums.
//  - sbf stored transposed sSt[j][row] so scale reads are conflict-free
//    broadcast ds_read_b128 (4 consecutive rows = the C-fragment's r dim).
// ---------------------------------------------------------------------------
template <bool WB>
__global__ __launch_bounds__(512, 4) void triplet_mfma(
    const float* __restrict__ rbf, const float* __restrict__ m,
    const float* __restrict__ o, const int* __restrict__ lg_src,
    const int* __restrict__ lg_dst, const float* __restrict__ W_sbf,
    const float* __restrict__ W_bilin_f, const short* __restrict__ W_bilin_h,
    float* __restrict__ m_update, int L) {
  __shared__ short aS[2048 * 8];    // 32 KB: A frags [mtile(8)][ks(4)][lane][8]
  __shared__ float sSt[NB][TL];     // 4 KB: sbf transposed [j][triplet]
  __shared__ int srcS[TL];
  __shared__ int dstS[TL];

  const int tid = threadIdx.x;
  const int lane = tid & 63;
  const int wv = tid >> 6;
  const long base = (long)blockIdx.x * TL;

  if (tid < TL) {
    long l = base + tid;
    int lc = (l < L) ? (int)l : 0;
    srcS[tid] = lg_src[lc];
    dstS[tid] = (l < L) ? lg_dst[lc] : -1;
  }
  __syncthreads();

  // ---- stage A: gather m rows (fp32), convert to bf16, fragment order ----
#pragma unroll
  for (int iter = 0; iter < 4; ++iter) {
    int s = iter * 512 + tid;             // slot 0..2047
    int c = s >> 6, l2 = s & 63;
    int mt = c >> 2, ks = c & 3;
    int row = mt * 16 + (l2 & 15);
    int k = ks * 32 + (l2 >> 4) * 8;
    const float* src = m + (long)srcS[row] * EMB + k;
    float4 v0 = *(const float4*)src;
    float4 v1 = *(const float4*)(src + 4);
    short8 hh;
    hh[0] = f2bf(v0.x); hh[1] = f2bf(v0.y); hh[2] = f2bf(v0.z); hh[3] = f2bf(v0.w);
    hh[4] = f2bf(v1.x); hh[5] = f2bf(v1.y); hh[6] = f2bf(v1.z); hh[7] = f2bf(v1.w);
    *(short8*)&aS[s * 8] = hh;
  }

  // ---- sbf per triplet (threads 0..127), fp32, transposed store ----
  if (tid < TL) {
    long l = base + tid;
    int lc = (l < L) ? (int)l : 0;
    int src = srcS[tid];
    int dst = lg_dst[lc];
    float r1x = o[src * 3 + 0], r1y = o[src * 3 + 1], r1z = o[src * 3 + 2];
    float r2x = o[dst * 3 + 0], r2y = o[dst * 3 + 1], r2z = o[dst * 3 + 2];
    float dotv = r1x * r2x + r1y * r2y + r1z * r2z;
    float cx = r1y * r2z - r1z * r2y;
    float cy = r1z * r2x - r1x * r2z;
    float cz = r1x * r2y - r1y * r2x;
    float crs = sqrtf(cx * cx + cy * cy + cz * cz);
    float angle = atan2f(crs, dotv);
    float cbf[NS];
#pragma unroll
    for (int s_ = 0; s_ < NS; ++s_) cbf[s_] = cosf(angle * (float)s_);
    float rb[NR];
#pragma unroll
    for (int r = 0; r < NR; ++r) rb[r] = rbf[src * NR + r];
#pragma unroll
    for (int b = 0; b < NB; ++b) {
      float sb = 0.f;
#pragma unroll
      for (int s_ = 0; s_ < NS; ++s_) {
        float t = 0.f;
#pragma unroll
        for (int r = 0; r < NR; ++r)
          t += rb[r] * W_sbf[(s_ * NR + r) * NB + b];
        sb += cbf[s_] * t;
      }
      sSt[b][tid] = sb;
    }
  }
  __syncthreads();
  // ------------- no further barriers until kernel end -------------

  const int mh = wv >> 2;        // M-half
  const int n0 = (wv & 3) * 2;   // first N-tile
  const int kq = lane >> 4;
  const int col16 = lane & 15;

  float accf[4][2][4];
#pragma unroll
  for (int mt = 0; mt < 4; ++mt)
#pragma unroll
    for (int nn = 0; nn < 2; ++nn)
#pragma unroll
      for (int r = 0; r < 4; ++r) accf[mt][nn][r] = 0.f;

  // B-fragment base offsets (elements): i = (n0+nn)*16 + col16
  const long ib0 = (long)((n0 + 0) * 16 + col16) * NB * EMB + kq * 8;
  const long ib1 = (long)((n0 + 1) * 16 + col16) * NB * EMB + kq * 8;

#pragma unroll 1
  for (int ks = 0; ks < 4; ++ks) {
    short8 A[4];
#pragma unroll
    for (int mt = 0; mt < 4; ++mt)
      A[mt] = *(const short8*)&aS[(((mh * 4 + mt) * 4 + ks) * 64 + lane) * 8];

#pragma unroll
    for (int j = 0; j < NB; ++j) {
      short8 b0, b1;
      if (WB) {
        b0 = *(const short8*)(W_bilin_h + ib0 + j * EMB + ks * 32);
        b1 = *(const short8*)(W_bilin_h + ib1 + j * EMB + ks * 32);
      } else {
        const float* p0 = W_bilin_f + ib0 + j * EMB + ks * 32;
        const float* p1 = W_bilin_f + ib1 + j * EMB + ks * 32;
        float4 u0 = *(const float4*)p0, u1 = *(const float4*)(p0 + 4);
        float4 u2 = *(const float4*)p1, u3 = *(const float4*)(p1 + 4);
        b0[0] = f2bf(u0.x); b0[1] = f2bf(u0.y); b0[2] = f2bf(u0.z); b0[3] = f2bf(u0.w);
        b0[4] = f2bf(u1.x); b0[5] = f2bf(u1.y); b0[6] = f2bf(u1.z); b0[7] = f2bf(u1.w);
        b1[0] = f2bf(u2.x); b1[1] = f2bf(u2.y); b1[2] = f2bf(u2.z); b1[3] = f2bf(u2.w);
        b1[4] = f2bf(u3.x); b1[5] = f2bf(u3.y); b1[6] = f2bf(u3.z); b1[7] = f2bf(u3.w);
      }
#pragma unroll
      for (int mt = 0; mt < 4; ++mt) {
        floatx4 c0 = __builtin_amdgcn_mfma_f32_16x16x32_bf16(
            A[mt], b0, (floatx4)0.f, 0, 0, 0);
        floatx4 c1 = __builtin_amdgcn_mfma_f32_16x16x32_bf16(
            A[mt], b1, (floatx4)0.f, 0, 0, 0);
        const floatx4 sv =
            *(const floatx4*)&sSt[j][(mh * 4 + mt) * 16 + kq * 4];
#pragma unroll
        for (int r = 0; r < 4; ++r) {
          accf[mt][0][r] += sv[r] * c0[r];
          accf[mt][1][r] += sv[r] * c1[r];
        }
      }
    }
  }

  // ---- scatter-add into m_update ----
#pragma unroll
  for (int mt = 0; mt < 4; ++mt) {
#pragma unroll
    for (int r = 0; r < 4; ++r) {
      int row = (mh * 4 + mt) * 16 + kq * 4 + r;
      int dst = dstS[row];
      if (dst >= 0) {
        float* p = m_update + (long)dst * EMB;
        unsafeAtomicAdd(p + (n0 + 0) * 16 + col16, accf[mt][0][r]);
        unsafeAtomicAdd(p + (n0 + 1) * 16 + col16, accf[mt][1][r]);
      }
    }
  }
}

// ---------------------------------------------------------------------------
extern "C" void kernel_launch(void* const* d_in, const int* in_sizes, int n_in,
                              void* d_out, int out_size, void* d_ws,
                              size_t ws_size, hipStream_t stream) {
  const float* rbf = (const float*)d_in[0];
  const float* m = (const float*)d_in[1];
  const float* o = (const float*)d_in[2];
  const int* lg_src = (const int*)d_in[3];
  const int* lg_dst = (const int*)d_in[4];
  const float* W_rbf = (const float*)d_in[5];
  const float* W_m = (const float*)d_in[6];
  const float* b_m = (const float*)d_in[7];
  const float* W_sbf = (const float*)d_in[8];
  const float* W_bilin = (const float*)d_in[9];

  const int E = in_sizes[1] / EMB;
  const int L = in_sizes[3];

  float* w_out = (float*)d_out;
  float* m_update = (float*)d_out + (long)E * EMB;

  long n4 = (long)E * EMB / 4;
  zero_kernel<<<1024, 256, 0, stream>>>((float4*)m_update, n4);
  edge_w_kernel<<<2048, 256, 0, stream>>>(rbf, m, W_rbf, W_m, b_m, w_out, E);

  int nblk = (L + TL - 1) / TL;
  const int wn = EMB * NB * EMB;  // 131072
  if (ws_size >= (size_t)wn * sizeof(short)) {
    short* wh = (short*)d_ws;
    wcvt_kernel<<<(wn + 255) / 256, 256, 0, stream>>>(W_bilin, wh, wn);
    triplet_mfma<true><<<nblk, 512, 0, stream>>>(
        rbf, m, o, lg_src, lg_dst, W_sbf, nullptr, wh, m_update, L);
  } else {
    triplet_mfma<false><<<nblk, 512, 0, stream>>>(
        rbf, m, o, lg_src, lg_dst, W_sbf, W_bilin, nullptr, m_update, L);
  }
}

// Round 2
// 554.833 us; speedup vs baseline: 7.0840x; 7.0840x over previous
//
#include <hip/hip_runtime.h>
#include <math.h>

#define EMB 128
#define NR 6
#define NS 7
#define NB 8
#define TL 256   // triplets per block in the MFMA bilinear kernel
#define EPB 8    // edges per block-iteration in edge_w

typedef __attribute__((ext_vector_type(8))) short short8;   // 8 bf16 = 4 VGPR
typedef __attribute__((ext_vector_type(4))) float floatx4;  // MFMA C/D

__device__ __forceinline__ short f2bf(float f) {  // fp32 -> bf16 RNE
  unsigned int u = __float_as_uint(f);
  u = u + 0x7fff + ((u >> 16) & 1);
  return (short)(u >> 16);
}

// ---------------------------------------------------------------------------
__global__ void zero_kernel(float4* __restrict__ p, long n4) {
  long i = (long)blockIdx.x * blockDim.x + threadIdx.x;
  long stride = (long)gridDim.x * blockDim.x;
  float4 z; z.x = z.y = z.z = z.w = 0.f;
  for (; i < n4; i += stride) p[i] = z;
}

// W_bilin fp32 -> bf16 (same flat layout [i][j][k])
__global__ void wcvt_kernel(const float* __restrict__ w, short* __restrict__ o,
                            int n) {
  int i = blockIdx.x * 256 + threadIdx.x;
  if (i < n) o[i] = f2bf(w[i]);
}

// ---------------------------------------------------------------------------
// w = (rbf @ W_rbf) * silu(m @ W_m + b_m)        [E, EMB]
// 8 edges per iteration, coalesced float4 staging, 3 barriers per 8 edges.
// ---------------------------------------------------------------------------
__global__ __launch_bounds__(256) void edge_w_kernel(
    const float* __restrict__ rbf, const float* __restrict__ m,
    const float* __restrict__ W_rbf, const float* __restrict__ W_m,
    const float* __restrict__ b_m, float* __restrict__ w_out, int E) {
  __shared__ float ms[EPB * EMB];    // 4 KB staged m rows
  __shared__ float rs[EPB * 8];      // rbf rows, stride 8
  __shared__ float pacc[EPB * EMB];  // 4 KB cross-h partials

  const int tid = threadIdx.x;
  const int i = tid & 127;
  const int h = tid >> 7;

  float Wreg[64];
#pragma unroll
  for (int kk = 0; kk < 64; ++kk) Wreg[kk] = W_m[(h * 64 + kk) * EMB + i];
  float wr[NR];
#pragma unroll
  for (int r = 0; r < NR; ++r) wr[r] = W_rbf[r * EMB + i];
  const float bm = b_m[i];

  const int ngrp = (E + EPB - 1) / EPB;
  for (int g = blockIdx.x; g < ngrp; g += gridDim.x) {
    const long e0 = (long)g * EPB;
    const int nv = min(EPB, (int)(E - e0));
    __syncthreads();  // previous iteration's ms/pacc/rs fully consumed
    if (nv == EPB) {
      ((float4*)ms)[tid] = ((const float4*)(m + e0 * EMB))[tid];
    } else {
      int er = (tid * 4) >> 7;
      if (er < nv) ((float4*)ms)[tid] = ((const float4*)(m + e0 * EMB))[tid];
    }
    if (tid < EPB * NR) {
      int er = tid / NR, r = tid - er * NR;
      if (er < nv) rs[er * 8 + r] = rbf[(e0 + er) * NR + r];
    }
    __syncthreads();

    float acc[EPB];
#pragma unroll
    for (int er = 0; er < EPB; ++er) acc[er] = 0.f;
    const float4* mv4 = (const float4*)ms;  // index: er*32 + h*16 + q
#pragma unroll
    for (int q = 0; q < 16; ++q) {
#pragma unroll
      for (int er = 0; er < EPB; ++er) {
        float4 mv = mv4[er * 32 + h * 16 + q];  // broadcast LDS read
        acc[er] += Wreg[q * 4 + 0] * mv.x + Wreg[q * 4 + 1] * mv.y +
                   Wreg[q * 4 + 2] * mv.z + Wreg[q * 4 + 3] * mv.w;
      }
    }
    if (h == 1) {
#pragma unroll
      for (int er = 0; er < EPB; ++er) pacc[er * EMB + i] = acc[er];
    }
    __syncthreads();
    if (h == 0) {
#pragma unroll
      for (int er = 0; er < EPB; ++er) {
        if (er < nv) {
          float x = acc[er] + pacc[er * EMB + i] + bm;
          float sig = 1.f / (1.f + expf(-x));
          float act = x * sig;
          float ar = 0.f;
#pragma unroll
          for (int r = 0; r < NR; ++r) ar += wr[r] * rs[er * 8 + r];
          w_out[(e0 + er) * EMB + i] = ar * act;
        }
      }
    }
  }
}

// ---------------------------------------------------------------------------
// helper: load one B fragment (16 B) either bf16-direct or fp32+convert
// ---------------------------------------------------------------------------
template <bool WB>
__device__ __forceinline__ short8 ldB(const float* __restrict__ wf,
                                      const short* __restrict__ wh, long off) {
  if (WB) {
    return *(const short8*)(wh + off);
  } else {
    float4 u0 = *(const float4*)(wf + off);
    float4 u1 = *(const float4*)(wf + off + 4);
    short8 h;
    h[0] = f2bf(u0.x); h[1] = f2bf(u0.y); h[2] = f2bf(u0.z); h[3] = f2bf(u0.w);
    h[4] = f2bf(u1.x); h[5] = f2bf(u1.y); h[6] = f2bf(u1.z); h[7] = f2bf(u1.w);
    return h;
  }
}

// ---------------------------------------------------------------------------
// MFMA triplet kernel v3. TL=256 triplets/block, 512 threads = 8 waves.
// Wave wv owns M-tiles (wv>>2)*8..+7 (16 rows each) and N-tiles (wv&3)*2..+1.
// vs round-0 (455us, verified structure):
//  - TL 128->256: 2x MFMA work per barrier, half the blocks.
//  - wS double-buffered + T14 async-STAGE split: j+1's B global loads issue
//    BEFORE compute(j) (latency hides under 64 MFMAs + scale), ds_write to
//    the alternate buffer after compute, ONE barrier per j (was 2).
//    B staging stays block-cooperative via LDS -> inter-block temporal
//    locality keeps the 32KB j-slice L2-hot (round-1's per-lane scattered
//    register loads destroyed this: FETCH 175MB -> 5.4GB).
//  - A frags re-read from LDS per j (conflict-free lane-contiguous b128)
//    instead of 64 pinned VGPRs; MFMA C-chains over ks, scale once per
//    (j,mt,nn). VGPR ~150 under the 256 cap (launch_bounds(512,2); LDS
//    138KB already limits to 1 block/CU, so registers are free).
// ---------------------------------------------------------------------------
template <bool WB>
__global__ __launch_bounds__(512, 2) void triplet_mfma(
    const float* __restrict__ rbf, const float* __restrict__ m,
    const float* __restrict__ o, const int* __restrict__ lg_src,
    const int* __restrict__ lg_dst, const float* __restrict__ W_sbf,
    const float* __restrict__ W_bilin_f, const short* __restrict__ W_bilin_h,
    float* __restrict__ m_update, int L) {
  __shared__ short aS[4096 * 8];     // 64 KB: A frags [mtG(16)][ks(4)][lane][8]
  __shared__ short wS[2][2048 * 8];  // 64 KB: B frags dbuf [ks(4)][nt(8)][lane][8]
  __shared__ float sSt[NB][TL];      // 8 KB: sbf transposed [j][triplet]
  __shared__ int srcS[TL];
  __shared__ int dstS[TL];

  const int tid = threadIdx.x;
  const int lane = tid & 63;
  const int wv = tid >> 6;
  const long base = (long)blockIdx.x * TL;

  if (tid < TL) {
    long l = base + tid;
    int lc = (l < L) ? (int)l : 0;
    srcS[tid] = lg_src[lc];
    dstS[tid] = (l < L) ? lg_dst[lc] : -1;
  }
  __syncthreads();

  // ---- stage A: gather m rows (fp32), convert to bf16, fragment order ----
#pragma unroll
  for (int iter = 0; iter < 8; ++iter) {
    int s = iter * 512 + tid;             // slot 0..4095
    int c = s >> 6, l2 = s & 63;
    int mt = c >> 2, ks = c & 3;          // mt 0..15
    int row = mt * 16 + (l2 & 15);        // 0..255
    int k = ks * 32 + (l2 >> 4) * 8;
    const float* src = m + (long)srcS[row] * EMB + k;
    float4 v0 = *(const float4*)src;
    float4 v1 = *(const float4*)(src + 4);
    short8 hh;
    hh[0] = f2bf(v0.x); hh[1] = f2bf(v0.y); hh[2] = f2bf(v0.z); hh[3] = f2bf(v0.w);
    hh[4] = f2bf(v1.x); hh[5] = f2bf(v1.y); hh[6] = f2bf(v1.z); hh[7] = f2bf(v1.w);
    *(short8*)&aS[s * 8] = hh;
  }

  // ---- sbf per triplet (threads 0..255), fp32, transposed store ----
  if (tid < TL) {
    long l = base + tid;
    int lc = (l < L) ? (int)l : 0;
    int src = srcS[tid];
    int dst = lg_dst[lc];
    float r1x = o[src * 3 + 0], r1y = o[src * 3 + 1], r1z = o[src * 3 + 2];
    float r2x = o[dst * 3 + 0], r2y = o[dst * 3 + 1], r2z = o[dst * 3 + 2];
    float dotv = r1x * r2x + r1y * r2y + r1z * r2z;
    float cx = r1y * r2z - r1z * r2y;
    float cy = r1z * r2x - r1x * r2z;
    float cz = r1x * r2y - r1y * r2x;
    float crs = sqrtf(cx * cx + cy * cy + cz * cz);
    float angle = atan2f(crs, dotv);
    float cbf[NS];
#pragma unroll
    for (int s_ = 0; s_ < NS; ++s_) cbf[s_] = cosf(angle * (float)s_);
    float rb[NR];
#pragma unroll
    for (int r = 0; r < NR; ++r) rb[r] = rbf[src * NR + r];
#pragma unroll
    for (int b = 0; b < NB; ++b) {
      float sb = 0.f;
#pragma unroll
      for (int s_ = 0; s_ < NS; ++s_) {
        float t = 0.f;
#pragma unroll
        for (int r = 0; r < NR; ++r)
          t += rb[r] * W_sbf[(s_ * NR + r) * NB + b];
        sb += cbf[s_] * t;
      }
      sSt[b][tid] = sb;
    }
  }

  // ---- per-thread B staging geometry (4 slots: q*512+tid) ----
  long bOff[4];  // element offset of (i, j=0, k) in W_bilin flat [i][j][k]
#pragma unroll
  for (int q = 0; q < 4; ++q) {
    int s2 = q * 512 + tid;
    int c2 = s2 >> 6;
    int ks = c2 >> 3, nt = c2 & 7;
    int i = nt * 16 + (lane & 15);
    int k = ks * 32 + (lane >> 4) * 8;
    bOff[q] = (long)i * NB * EMB + k;
  }

  // ---- stage B(j=0) into wS[0] ----
#pragma unroll
  for (int q = 0; q < 4; ++q) {
    short8 hh = ldB<WB>(W_bilin_f, W_bilin_h, bOff[q]);
    *(short8*)&wS[0][(q * 512 + tid) * 8] = hh;
  }
  __syncthreads();  // aS + sSt + wS[0] all ready

  const int mh = wv >> 2;        // M-half (0/1): m-tiles mh*8..mh*8+7
  const int n0 = (wv & 3) * 2;   // first N-tile
  const int kq = lane >> 4;
  const int col16 = lane & 15;

  float accf[8][2][4];
#pragma unroll
  for (int mt = 0; mt < 8; ++mt)
#pragma unroll
    for (int nn = 0; nn < 2; ++nn)
#pragma unroll
      for (int r = 0; r < 4; ++r) accf[mt][nn][r] = 0.f;

  int buf = 0;
#pragma unroll 1
  for (int j = 0; j < NB; ++j) {
    // ---- T14 issue-early: prefetch B(j+1) into registers ----
    short8 pre0, pre1, pre2, pre3;
    if (j < NB - 1) {
      const long jo = (long)(j + 1) * EMB;
      pre0 = ldB<WB>(W_bilin_f, W_bilin_h, bOff[0] + jo);
      pre1 = ldB<WB>(W_bilin_f, W_bilin_h, bOff[1] + jo);
      pre2 = ldB<WB>(W_bilin_f, W_bilin_h, bOff[2] + jo);
      pre3 = ldB<WB>(W_bilin_f, W_bilin_h, bOff[3] + jo);
    }

    // ---- compute j from wS[buf] ----
    short8 Bf[4][2];
#pragma unroll
    for (int ks = 0; ks < 4; ++ks) {
      Bf[ks][0] = *(const short8*)&wS[buf][((ks * 8 + n0 + 0) * 64 + lane) * 8];
      Bf[ks][1] = *(const short8*)&wS[buf][((ks * 8 + n0 + 1) * 64 + lane) * 8];
    }
#pragma unroll
    for (int mt = 0; mt < 8; ++mt) {
      const int mtG = mh * 8 + mt;
      floatx4 C0 = (floatx4)0.f, C1 = (floatx4)0.f;
#pragma unroll
      for (int ks = 0; ks < 4; ++ks) {
        short8 A = *(const short8*)&aS[((mtG * 4 + ks) * 64 + lane) * 8];
        C0 = __builtin_amdgcn_mfma_f32_16x16x32_bf16(A, Bf[ks][0], C0, 0, 0, 0);
        C1 = __builtin_amdgcn_mfma_f32_16x16x32_bf16(A, Bf[ks][1], C1, 0, 0, 0);
      }
      const floatx4 sv = *(const floatx4*)&sSt[j][mtG * 16 + kq * 4];
#pragma unroll
      for (int r = 0; r < 4; ++r) {
        accf[mt][0][r] += sv[r] * C0[r];
        accf[mt][1][r] += sv[r] * C1[r];
      }
    }

    // ---- write-late: prefetched B(j+1) -> wS[buf^1] ----
    // (safe: last readers of wS[buf^1] finished at the end-of-(j-1) barrier)
    if (j < NB - 1) {
      *(short8*)&wS[buf ^ 1][(0 * 512 + tid) * 8] = pre0;
      *(short8*)&wS[buf ^ 1][(1 * 512 + tid) * 8] = pre1;
      *(short8*)&wS[buf ^ 1][(2 * 512 + tid) * 8] = pre2;
      *(short8*)&wS[buf ^ 1][(3 * 512 + tid) * 8] = pre3;
    }
    __syncthreads();  // one barrier per j: wS[buf^1] visible, wS[buf] retired
    buf ^= 1;
  }

  // ---- scatter-add into m_update ----
#pragma unroll
  for (int mt = 0; mt < 8; ++mt) {
#pragma unroll
    for (int r = 0; r < 4; ++r) {
      int row = (mh * 8 + mt) * 16 + kq * 4 + r;
      int dst = dstS[row];
      if (dst >= 0) {
        float* p = m_update + (long)dst * EMB;
        unsafeAtomicAdd(p + (n0 + 0) * 16 + col16, accf[mt][0][r]);
        unsafeAtomicAdd(p + (n0 + 1) * 16 + col16, accf[mt][1][r]);
      }
    }
  }
}

// ---------------------------------------------------------------------------
extern "C" void kernel_launch(void* const* d_in, const int* in_sizes, int n_in,
                              void* d_out, int out_size, void* d_ws,
                              size_t ws_size, hipStream_t stream) {
  const float* rbf = (const float*)d_in[0];
  const float* m = (const float*)d_in[1];
  const float* o = (const float*)d_in[2];
  const int* lg_src = (const int*)d_in[3];
  const int* lg_dst = (const int*)d_in[4];
  const float* W_rbf = (const float*)d_in[5];
  const float* W_m = (const float*)d_in[6];
  const float* b_m = (const float*)d_in[7];
  const float* W_sbf = (const float*)d_in[8];
  const float* W_bilin = (const float*)d_in[9];

  const int E = in_sizes[1] / EMB;
  const int L = in_sizes[3];

  float* w_out = (float*)d_out;
  float* m_update = (float*)d_out + (long)E * EMB;

  long n4 = (long)E * EMB / 4;
  zero_kernel<<<1024, 256, 0, stream>>>((float4*)m_update, n4);
  edge_w_kernel<<<2048, 256, 0, stream>>>(rbf, m, W_rbf, W_m, b_m, w_out, E);

  int nblk = (L + TL - 1) / TL;
  const int wn = EMB * NB * EMB;  // 131072
  if (ws_size >= (size_t)wn * sizeof(short)) {
    short* wh = (short*)d_ws;
    wcvt_kernel<<<(wn + 255) / 256, 256, 0, stream>>>(W_bilin, wh, wn);
    triplet_mfma<true><<<nblk, 512, 0, stream>>>(
        rbf, m, o, lg_src, lg_dst, W_sbf, nullptr, wh, m_update, L);
  } else {
    triplet_mfma<false><<<nblk, 512, 0, stream>>>(
        rbf, m, o, lg_src, lg_dst, W_sbf, W_bilin, nullptr, m_update, L);
  }
}